// Round 3
// baseline (689.622 us; speedup 1.0000x reference)
//
#include <hip/hip_runtime.h>
#include <stdint.h>

#define MQ 256
#define NB 50000
#define KD 2048
#define BN 64
#define BK 64
#define KT (KD / BK)
#define NBLK ((NB + BN - 1) / BN)  // 782

typedef __attribute__((ext_vector_type(8))) short bf16x8;
typedef __attribute__((ext_vector_type(4))) float f32x4;

__device__ __forceinline__ unsigned int pack_bf16(float a, float b) {
  unsigned int ua = __float_as_uint(a);
  ua += 0x7fffu + ((ua >> 16) & 1u);
  unsigned int ub = __float_as_uint(b);
  ub += 0x7fffu + ((ub >> 16) & 1u);
  return (ua >> 16) | (ub & 0xffff0000u);
}

// order-preserving float<->uint map (total order, works for negatives)
__device__ __forceinline__ unsigned int ordf(float f) {
  unsigned int u = __float_as_uint(f);
  return (u & 0x80000000u) ? ~u : (u | 0x80000000u);
}
__device__ __forceinline__ float deordf(unsigned int e) {
  unsigned int u = (e & 0x80000000u) ? (e ^ 0x80000000u) : ~e;
  return __uint_as_float(u);
}

__device__ __forceinline__ float wave_sum(float v) {
#pragma unroll
  for (int o = 32; o > 0; o >>= 1) v += __shfl_down(v, o, 64);
  return v;
}

// ---------------- kernel 1: queries fp32 -> bf16 (+ q norms) ----------------
__global__ __launch_bounds__(256) void prep_q(const float* __restrict__ q,
                                              unsigned short* __restrict__ qbf,
                                              float* __restrict__ qn) {
  const int b = blockIdx.x, tid = threadIdx.x;
  const float* row = q + (size_t)b * KD;
  float4 v0 = *(const float4*)(row + tid * 8);
  float4 v1 = *(const float4*)(row + tid * 8 + 4);
  float sq = v0.x * v0.x + v0.y * v0.y + v0.z * v0.z + v0.w * v0.w +
             v1.x * v1.x + v1.y * v1.y + v1.z * v1.z + v1.w * v1.w;
  uint4 o;
  o.x = pack_bf16(v0.x, v0.y);
  o.y = pack_bf16(v0.z, v0.w);
  o.z = pack_bf16(v1.x, v1.y);
  o.w = pack_bf16(v1.z, v1.w);
  *(uint4*)(qbf + (size_t)b * KD + tid * 8) = o;
  sq = wave_sum(sq);
  __shared__ float s4[4];
  if ((tid & 63) == 0) s4[tid >> 6] = sq;
  __syncthreads();
  if (tid == 0) qn[b] = sqrtf(s4[0] + s4[1] + s4[2] + s4[3]);
}

// ---------------- kernel 2: bf16 MFMA GEMM, A-direct, Bs-dbuf --------------
// 256(M) x 64(N) tile, BK=64. Restructured vs previous version:
//  * A (qbf, 1 MB, L2-resident) is loaded DIRECTLY global->register as MFMA
//    fragments (16B/lane, 16 fully-used 64B lines per instruction) — the A
//    LDS tile, its 8 global_load_lds per K-step, and the second barrier are
//    gone. LDS: 42 KB -> 18 KB.
//  * Bs (the HBM stream, converted to bf16) is DOUBLE-buffered: consume of
//    tile kt+1 writes Bs[p^1] while other waves still read Bs[p] -> exactly
//    ONE __syncthreads() per K-step. At that barrier the in-flight B count
//    is naturally zero (tile kt+2 is issued after it), so the implicit
//    vmcnt(0) drain is free — no inline-asm barrier discipline needed.
//  * Bs keeps the XOR swizzle (elem ^= (row&7)*8) on write and read.
//  MFMA inputs are bitwise identical to the previous version -> same absmax.
__global__ __launch_bounds__(256, 3) void gemm_scores(
    const float* __restrict__ bank, const unsigned short* __restrict__ qbf,
    const float* __restrict__ qn, float* __restrict__ out_scores,
    unsigned long long* __restrict__ bm) {
  __shared__ alignas(16) unsigned short Bs[2][BN * BK];  // 2 x 8 KB, swizzled
  __shared__ float qn_s[MQ];
  __shared__ float bsq_s[256];
  __shared__ float bn_s[BN];

  const int tid = threadIdx.x;
  const int w = tid >> 6;
  const int lane = tid & 63;
  const int n0 = blockIdx.x * BN;

  qn_s[tid] = qn[tid];

  f32x4 acc[4][4] = {};

  // B staging map: thread t -> block-local row t>>2, 64B k-chunk (t&3)*16
  const int br = tid >> 2;
  const int bseg = (tid & 3) * 16;
  const int be0 = bseg ^ ((br & 7) * 8);  // swizzled write slot
  int brow = n0 + br;
  if (brow >= NB) brow = NB - 1;  // clamp; excluded at store
  const float* bsrc = bank + (size_t)brow * KD + bseg;

  // A fragment base pointers (per tm sub-tile), loop-invariant per-lane part
  const int quad4 = lane >> 4;
  const unsigned short* abase[4];
#pragma unroll
  for (int t = 0; t < 4; ++t)
    abase[t] = qbf + (size_t)(w * 64 + t * 16 + (lane & 15)) * KD + quad4 * 8;

  float bsq = 0.f;
  float4 f0, f1, f2, f3;

  // ---- prologue: tile 0 -> Bs[0]; then issue tile 1 ----
  f0 = *(const float4*)(bsrc);
  f1 = *(const float4*)(bsrc + 4);
  f2 = *(const float4*)(bsrc + 8);
  f3 = *(const float4*)(bsrc + 12);
  {
    bsq += f0.x * f0.x + f0.y * f0.y + f0.z * f0.z + f0.w * f0.w +
           f1.x * f1.x + f1.y * f1.y + f1.z * f1.z + f1.w * f1.w +
           f2.x * f2.x + f2.y * f2.y + f2.z * f2.z + f2.w * f2.w +
           f3.x * f3.x + f3.y * f3.y + f3.z * f3.z + f3.w * f3.w;
    uint4 p0, p1;
    p0.x = pack_bf16(f0.x, f0.y);
    p0.y = pack_bf16(f0.z, f0.w);
    p0.z = pack_bf16(f1.x, f1.y);
    p0.w = pack_bf16(f1.z, f1.w);
    p1.x = pack_bf16(f2.x, f2.y);
    p1.y = pack_bf16(f2.z, f2.w);
    p1.z = pack_bf16(f3.x, f3.y);
    p1.w = pack_bf16(f3.z, f3.w);
    *(uint4*)&Bs[0][br * BK + be0] = p0;
    *(uint4*)&Bs[0][br * BK + (be0 ^ 8)] = p1;
  }
  __syncthreads();
  {
    const float* p = bsrc + BK;
    f0 = *(const float4*)(p);
    f1 = *(const float4*)(p + 4);
    f2 = *(const float4*)(p + 8);
    f3 = *(const float4*)(p + 12);
  }

  for (int kt = 0; kt < KT; ++kt) {
    const int p = kt & 1;
    // ---- compute tile kt: A direct from L2, B from Bs[p] (swizzled) ----
#pragma unroll
    for (int s = 0; s < 2; ++s) {
      const int kx = (s * 32 + quad4 * 8) ^ ((lane & 7) * 8);
      bf16x8 af[4], bfv[4];
#pragma unroll
      for (int t = 0; t < 4; ++t) {
        af[t] = *(const bf16x8*)(abase[t] + kt * BK + s * 32);
        bfv[t] = *(const bf16x8*)&Bs[p][(t * 16 + (lane & 15)) * BK + kx];
      }
#pragma unroll
      for (int tm = 0; tm < 4; ++tm)
#pragma unroll
        for (int tn = 0; tn < 4; ++tn)
          acc[tm][tn] = __builtin_amdgcn_mfma_f32_16x16x32_bf16(
              af[tm], bfv[tn], acc[tm][tn], 0, 0, 0);
    }
    if (kt + 1 < KT) {
      // ---- consume tile kt+1 regs -> Bs[p^1] (other buffer: no race with
      //      concurrent readers of Bs[p]) ----
      bsq += f0.x * f0.x + f0.y * f0.y + f0.z * f0.z + f0.w * f0.w +
             f1.x * f1.x + f1.y * f1.y + f1.z * f1.z + f1.w * f1.w +
             f2.x * f2.x + f2.y * f2.y + f2.z * f2.z + f2.w * f2.w +
             f3.x * f3.x + f3.y * f3.y + f3.z * f3.z + f3.w * f3.w;
      uint4 p0, p1;
      p0.x = pack_bf16(f0.x, f0.y);
      p0.y = pack_bf16(f0.z, f0.w);
      p0.z = pack_bf16(f1.x, f1.y);
      p0.w = pack_bf16(f1.z, f1.w);
      p1.x = pack_bf16(f2.x, f2.y);
      p1.y = pack_bf16(f2.z, f2.w);
      p1.z = pack_bf16(f3.x, f3.y);
      p1.w = pack_bf16(f3.z, f3.w);
      *(uint4*)&Bs[p ^ 1][br * BK + be0] = p0;
      *(uint4*)&Bs[p ^ 1][br * BK + (be0 ^ 8)] = p1;
      // barrier: all reads of Bs[p] and writes of Bs[p^1] complete. No B
      // loads are in flight here, so the vmcnt(0) inside is free.
      __syncthreads();
      // ---- issue tile kt+2 AFTER the barrier (covered by next compute) ----
      if (kt + 2 < KT) {
        const float* pp = bsrc + (kt + 2) * BK;
        f0 = *(const float4*)(pp);
        f1 = *(const float4*)(pp + 4);
        f2 = *(const float4*)(pp + 8);
        f3 = *(const float4*)(pp + 12);
      }
    }
  }

  // ---- b-norm reduce: 4 partials per row ----
  __syncthreads();
  bsq_s[tid] = bsq;
  __syncthreads();
  if (tid < BN)
    bn_s[tid] = sqrtf(bsq_s[tid * 4] + bsq_s[tid * 4 + 1] + bsq_s[tid * 4 + 2] +
                      bsq_s[tid * 4 + 3]);
  __syncthreads();

  // ---- epilogue: scale, store, and per-(block,m) packed argmax ----
  const int quad = lane >> 4, nl = lane & 15;
#pragma unroll
  for (int tm = 0; tm < 4; ++tm) {
#pragma unroll
    for (int r = 0; r < 4; ++r) {
      const int m = w * 64 + tm * 16 + quad * 4 + r;
      const float qm = qn_s[m];
      unsigned long long best = 0ull;
#pragma unroll
      for (int tn = 0; tn < 4; ++tn) {
        const int gn = n0 + tn * 16 + nl;
        if (gn < NB) {
          const float sc =
              acc[tm][tn][r] / fmaxf(qm * bn_s[tn * 16 + nl], 1e-12f);
          out_scores[(size_t)m * NB + gn] = sc;
          const unsigned long long pk =
              ((unsigned long long)ordf(sc) << 32) | (unsigned int)gn;
          best = pk > best ? pk : best;
        }
      }
#pragma unroll
      for (int mask = 1; mask < 16; mask <<= 1) {
        const unsigned long long o = __shfl_xor(best, mask, 64);
        best = o > best ? o : best;
      }
      if (nl == 0) bm[(size_t)m * NBLK + blockIdx.x] = best;
    }
  }
}

// ---------------- kernel 3: argmax from block maxima + fp32 rescue ---------
// Global approx max from the 782 packed block maxima; blocks within
// delta=2e-3 of the max get their 64-score segment rescanned; candidates get
// exact fp32 rescoring (argmax of dot/bn is monotonic-equal to the reference
// score since qn is constant per row).
__global__ __launch_bounds__(256) void argmax_rescue(
    const unsigned long long* __restrict__ bm, const float* __restrict__ scores,
    const float* __restrict__ q, const float* __restrict__ bank,
    float* __restrict__ out_idx) {
  const int b = blockIdx.x, tid = threadIdx.x;
  const int w = tid >> 6, lane = tid & 63;
  const unsigned long long* rbm = bm + (size_t)b * NBLK;

  unsigned long long pmax = 0ull;
  for (int i = tid; i < NBLK; i += 256) {
    const unsigned long long v = rbm[i];
    pmax = v > pmax ? v : pmax;
  }
#pragma unroll
  for (int o = 32; o > 0; o >>= 1) {
    const unsigned long long v = __shfl_down(pmax, o, 64);
    pmax = v > pmax ? v : pmax;
  }
  __shared__ unsigned long long red[4];
  if (lane == 0) red[w] = pmax;
  __syncthreads();
  unsigned long long gmax = red[0];
#pragma unroll
  for (int i = 1; i < 4; ++i) gmax = red[i] > gmax ? red[i] : gmax;
  const float thr = deordf((unsigned int)(gmax >> 32)) - 2e-3f;

  __shared__ int cand[64];
  __shared__ int cnt;
  if (tid == 0) cnt = 0;
  __syncthreads();
  const float* srow = scores + (size_t)b * NB;
  for (int i = tid; i < NBLK; i += 256) {
    const float bmf = deordf((unsigned int)(rbm[i] >> 32));
    if (bmf >= thr) {  // rare (1-3 blocks): rescan its 64 scores
      const int base = i * BN;
      const int lim = min(BN, NB - base);
      for (int j = 0; j < lim; ++j) {
        if (srow[base + j] >= thr) {
          const int c = atomicAdd(&cnt, 1);
          if (c < 64) cand[c] = base + j;
        }
      }
    }
  }
  __syncthreads();
  const int nc = min(cnt, 64);

  __shared__ float dd[4], ss[4];
  float best = -1e30f;
  int bidx = 0x7fffffff;
  const float* qrow = q + (size_t)b * KD;
  for (int c = 0; c < nc; ++c) {
    const int idx = cand[c];
    const float* brow = bank + (size_t)idx * KD;
    float4 bv0 = *(const float4*)(brow + tid * 8);
    float4 bv1 = *(const float4*)(brow + tid * 8 + 4);
    float4 qv0 = *(const float4*)(qrow + tid * 8);
    float4 qv1 = *(const float4*)(qrow + tid * 8 + 4);
    float d = 0.f, s = 0.f;
    d = fmaf(qv0.x, bv0.x, d);
    s = fmaf(bv0.x, bv0.x, s);
    d = fmaf(qv0.y, bv0.y, d);
    s = fmaf(bv0.y, bv0.y, s);
    d = fmaf(qv0.z, bv0.z, d);
    s = fmaf(bv0.z, bv0.z, s);
    d = fmaf(qv0.w, bv0.w, d);
    s = fmaf(bv0.w, bv0.w, s);
    d = fmaf(qv1.x, bv1.x, d);
    s = fmaf(bv1.x, bv1.x, s);
    d = fmaf(qv1.y, bv1.y, d);
    s = fmaf(bv1.y, bv1.y, s);
    d = fmaf(qv1.z, bv1.z, d);
    s = fmaf(bv1.z, bv1.z, s);
    d = fmaf(qv1.w, bv1.w, d);
    s = fmaf(bv1.w, bv1.w, s);
    d = wave_sum(d);
    s = wave_sum(s);
    if (lane == 0) {
      dd[w] = d;
      ss[w] = s;
    }
    __syncthreads();
    const float dt = dd[0] + dd[1] + dd[2] + dd[3];
    const float st = ss[0] + ss[1] + ss[2] + ss[3];
    const float sc = dt / fmaxf(sqrtf(st), 1e-12f);
    if (sc > best || (sc == best && idx < bidx)) {
      best = sc;
      bidx = idx;
    }
    __syncthreads();
  }
  if (tid == 0) out_idx[b] = (float)bidx;
}

extern "C" void kernel_launch(void* const* d_in, const int* in_sizes, int n_in,
                              void* d_out, int out_size, void* d_ws,
                              size_t ws_size, hipStream_t stream) {
  const float* queries = (const float*)d_in[0];  // [256, 2048] fp32
  const float* bank = (const float*)d_in[1];     // [50000, 2048] fp32
  float* out = (float*)d_out;                    // [256 idx | 256*50000 scores]
  float* out_scores = out + MQ;

  char* ws = (char*)d_ws;
  unsigned short* qbf = (unsigned short*)ws;                 // 1 MB bf16 queries
  float* qn = (float*)(ws + (size_t)MQ * KD * 2);            // 1 KB q-norms
  unsigned long long* bm =
      (unsigned long long*)(ws + (size_t)MQ * KD * 2 + 2048);  // 1.6 MB maxima

  prep_q<<<MQ, 256, 0, stream>>>(queries, qbf, qn);
  gemm_scores<<<NBLK, 256, 0, stream>>>(bank, qbf, qn, out_scores, bm);
  argmax_rescue<<<MQ, 256, 0, stream>>>(bm, out_scores, queries, bank, out);
}

// Round 4
// 635.094 us; speedup vs baseline: 1.0859x; 1.0859x over previous
//
#include <hip/hip_runtime.h>
#include <stdint.h>

#define MQ 256
#define NB 50000
#define KD 2048
#define BN 64
#define BK 64
#define KT (KD / BK)
#define NBLK ((NB + BN - 1) / BN)  // 782

typedef __attribute__((ext_vector_type(8))) short bf16x8;
typedef __attribute__((ext_vector_type(4))) float f32x4;

__device__ __forceinline__ unsigned int pack_bf16(float a, float b) {
  unsigned int ua = __float_as_uint(a);
  ua += 0x7fffu + ((ua >> 16) & 1u);
  unsigned int ub = __float_as_uint(b);
  ub += 0x7fffu + ((ub >> 16) & 1u);
  return (ua >> 16) | (ub & 0xffff0000u);
}

// order-preserving float<->uint map (total order, works for negatives)
__device__ __forceinline__ unsigned int ordf(float f) {
  unsigned int u = __float_as_uint(f);
  return (u & 0x80000000u) ? ~u : (u | 0x80000000u);
}
__device__ __forceinline__ float deordf(unsigned int e) {
  unsigned int u = (e & 0x80000000u) ? (e ^ 0x80000000u) : ~e;
  return __uint_as_float(u);
}

__device__ __forceinline__ float wave_sum(float v) {
#pragma unroll
  for (int o = 32; o > 0; o >>= 1) v += __shfl_down(v, o, 64);
  return v;
}

// ---------------- kernel 1: queries fp32 -> bf16 (+ q norms) ----------------
__global__ __launch_bounds__(256) void prep_q(const float* __restrict__ q,
                                              unsigned short* __restrict__ qbf,
                                              float* __restrict__ qn) {
  const int b = blockIdx.x, tid = threadIdx.x;
  const float* row = q + (size_t)b * KD;
  float4 v0 = *(const float4*)(row + tid * 8);
  float4 v1 = *(const float4*)(row + tid * 8 + 4);
  float sq = v0.x * v0.x + v0.y * v0.y + v0.z * v0.z + v0.w * v0.w +
             v1.x * v1.x + v1.y * v1.y + v1.z * v1.z + v1.w * v1.w;
  uint4 o;
  o.x = pack_bf16(v0.x, v0.y);
  o.y = pack_bf16(v0.z, v0.w);
  o.z = pack_bf16(v1.x, v1.y);
  o.w = pack_bf16(v1.z, v1.w);
  *(uint4*)(qbf + (size_t)b * KD + tid * 8) = o;
  sq = wave_sum(sq);
  __shared__ float s4[4];
  if ((tid & 63) == 0) s4[tid >> 6] = sq;
  __syncthreads();
  if (tid == 0) qn[b] = sqrtf(s4[0] + s4[1] + s4[2] + s4[3]);
}

// ---------------- kernel 2: fully pipelined bf16 MFMA GEMM ----------------
// 256(M) x 64(N) tile, BK=64, 512 threads (8 waves, M=32/wave).
// Latency-bound fix (counters r3: MfmaUtil 7.5, VALU 10, HBM 12%, all idle):
//  * A fragments are register-prefetched ONE kt ahead (2 banks, kt unrolled
//    by 2, static indices) -> L2 latency hidden under a full kt of MFMA.
//  * B stream (HBM fp32) loads are issued BEFORE the barrier and consumed a
//    full kt later (LDS dbuf): coverage ~1 kt >> 900cy HBM latency.
//  * raw "s_waitcnt lgkmcnt(0); s_barrier" instead of __syncthreads(): NO
//    vmcnt(0) drain -> A/B loads stay in flight across the barrier; the
//    compiler's exact counted vmcnt at each use point does the rest.
//    Race-free: pack writes go to Bs[p^1] while Bs[p] is read; lgkmcnt(0)
//    publishes the ds_writes before s_barrier.
//  * 8 waves x 32 rows: acc[2][4] (32 VGPR) + 2 A banks (32) + B regs (8)
//    keeps VGPR under the 128 occupancy cliff; __launch_bounds__(512,4)
//    -> 2 blocks/CU = 16 waves/CU.
__global__ __launch_bounds__(512, 4) void gemm_scores(
    const float* __restrict__ bank, const unsigned short* __restrict__ qbf,
    const float* __restrict__ qn, float* __restrict__ out_scores,
    unsigned long long* __restrict__ bm) {
  __shared__ alignas(16) unsigned short Bs[2][BN * BK];  // 2 x 8 KB, swizzled
  __shared__ float qn_s[MQ];
  __shared__ float bsq_s[512];
  __shared__ float bn_s[BN];

  const int tid = threadIdx.x;  // 0..511
  const int w = tid >> 6;       // 0..7
  const int lane = tid & 63;
  const int n0 = blockIdx.x * BN;

  if (tid < MQ) qn_s[tid] = qn[tid];

  f32x4 acc[2][4] = {};

  // B staging: thread t -> row t>>3, 8-float chunk (t&7)*8 (32B/thread/kt)
  const int br = tid >> 3;
  const int bc = (tid & 7) * 8;
  const int be0 = bc ^ ((br & 7) * 8);  // swizzled bf16 slot (16B aligned)
  int brow = n0 + br;
  if (brow >= NB) brow = NB - 1;  // clamp; excluded at store
  const float* bsrc = bank + (size_t)brow * KD + bc;

  // A fragment bases: rows w*32 + {0,16} + (lane&15), col quad4*8
  const int quad4 = lane >> 4;
  const unsigned short* ab0 =
      qbf + (size_t)(w * 32 + (lane & 15)) * KD + quad4 * 8;
  const unsigned short* ab1 = ab0 + (size_t)16 * KD;

  float bsq = 0.f;
  float4 g0, g1;

  // ---- prologue: B(0) -> Bs[0]; A(0) -> bank A; B(1) in flight ----
  g0 = *(const float4*)(bsrc);
  g1 = *(const float4*)(bsrc + 4);
  bsq += g0.x * g0.x + g0.y * g0.y + g0.z * g0.z + g0.w * g0.w +
         g1.x * g1.x + g1.y * g1.y + g1.z * g1.z + g1.w * g1.w;
  {
    uint4 pk;
    pk.x = pack_bf16(g0.x, g0.y);
    pk.y = pack_bf16(g0.z, g0.w);
    pk.z = pack_bf16(g1.x, g1.y);
    pk.w = pack_bf16(g1.z, g1.w);
    *(uint4*)&Bs[0][br * BK + be0] = pk;
  }
  bf16x8 aA0 = *(const bf16x8*)(ab0);
  bf16x8 aA1 = *(const bf16x8*)(ab0 + 32);
  bf16x8 aA2 = *(const bf16x8*)(ab1);
  bf16x8 aA3 = *(const bf16x8*)(ab1 + 32);
  g0 = *(const float4*)(bsrc + BK);
  g1 = *(const float4*)(bsrc + BK + 4);
  bf16x8 aB0, aB1, aB2, aB3;
  __syncthreads();  // prologue only: full drain acceptable once

  // One K-step: MFMA(kt) with CUR bank; prefetch A(kt+1) into NXT;
  // pack B(kt+1) -> Bs[(kt+1)&1]; issue B(kt+2); raw barrier (no vm drain).
#define GBODY(KT_, C0, C1, C2, C3, N0_, N1_, N2_, N3_)                        \
  do {                                                                        \
    const int kt_ = (KT_);                                                    \
    if (kt_ + 1 < KT) {                                                       \
      N0_ = *(const bf16x8*)(ab0 + (kt_ + 1) * BK);                           \
      N1_ = *(const bf16x8*)(ab0 + (kt_ + 1) * BK + 32);                      \
      N2_ = *(const bf16x8*)(ab1 + (kt_ + 1) * BK);                           \
      N3_ = *(const bf16x8*)(ab1 + (kt_ + 1) * BK + 32);                      \
    }                                                                         \
    const unsigned short* bsp = Bs[kt_ & 1];                                  \
    _Pragma("unroll") for (int s = 0; s < 2; ++s) {                           \
      const int kx = (s * 32 + quad4 * 8) ^ ((lane & 7) * 8);                 \
      bf16x8 bfv[4];                                                          \
      _Pragma("unroll") for (int t = 0; t < 4; ++t) bfv[t] =                  \
          *(const bf16x8*)&bsp[(t * 16 + (lane & 15)) * BK + kx];             \
      _Pragma("unroll") for (int tn = 0; tn < 4; ++tn) {                      \
        acc[0][tn] = __builtin_amdgcn_mfma_f32_16x16x32_bf16(                 \
            s ? C1 : C0, bfv[tn], acc[0][tn], 0, 0, 0);                       \
        acc[1][tn] = __builtin_amdgcn_mfma_f32_16x16x32_bf16(                 \
            s ? C3 : C2, bfv[tn], acc[1][tn], 0, 0, 0);                       \
      }                                                                       \
    }                                                                         \
    if (kt_ + 1 < KT) {                                                       \
      bsq += g0.x * g0.x + g0.y * g0.y + g0.z * g0.z + g0.w * g0.w +          \
             g1.x * g1.x + g1.y * g1.y + g1.z * g1.z + g1.w * g1.w;           \
      uint4 pk;                                                               \
      pk.x = pack_bf16(g0.x, g0.y);                                           \
      pk.y = pack_bf16(g0.z, g0.w);                                           \
      pk.z = pack_bf16(g1.x, g1.y);                                           \
      pk.w = pack_bf16(g1.z, g1.w);                                           \
      *(uint4*)&Bs[(kt_ + 1) & 1][br * BK + be0] = pk;                        \
      if (kt_ + 2 < KT) {                                                     \
        const float* pp = bsrc + (kt_ + 2) * BK;                              \
        g0 = *(const float4*)(pp);                                            \
        g1 = *(const float4*)(pp + 4);                                        \
      }                                                                       \
      asm volatile("s_waitcnt lgkmcnt(0)\n\ts_barrier" ::: "memory");         \
    }                                                                         \
  } while (0)

  for (int kt = 0; kt < KT; kt += 2) {
    GBODY(kt, aA0, aA1, aA2, aA3, aB0, aB1, aB2, aB3);
    GBODY(kt + 1, aB0, aB1, aB2, aB3, aA0, aA1, aA2, aA3);
  }
#undef GBODY

  // ---- b-norm reduce: 8 partials per row ----
  __syncthreads();
  bsq_s[tid] = bsq;
  __syncthreads();
  if (tid < BN) {
    float s = 0.f;
#pragma unroll
    for (int j = 0; j < 8; ++j) s += bsq_s[tid * 8 + j];
    bn_s[tid] = sqrtf(s);
  }
  __syncthreads();

  // ---- epilogue: scale, store, and per-(block,m) packed argmax ----
  const int quad = lane >> 4, nl = lane & 15;
#pragma unroll
  for (int tm = 0; tm < 2; ++tm) {
#pragma unroll
    for (int r = 0; r < 4; ++r) {
      const int m = w * 32 + tm * 16 + quad * 4 + r;
      const float qm = qn_s[m];
      unsigned long long best = 0ull;
#pragma unroll
      for (int tn = 0; tn < 4; ++tn) {
        const int gn = n0 + tn * 16 + nl;
        if (gn < NB) {
          const float sc =
              acc[tm][tn][r] / fmaxf(qm * bn_s[tn * 16 + nl], 1e-12f);
          out_scores[(size_t)m * NB + gn] = sc;
          const unsigned long long pk =
              ((unsigned long long)ordf(sc) << 32) | (unsigned int)gn;
          best = pk > best ? pk : best;
        }
      }
#pragma unroll
      for (int mask = 1; mask < 16; mask <<= 1) {
        const unsigned long long o = __shfl_xor(best, mask, 64);
        best = o > best ? o : best;
      }
      if (nl == 0) bm[(size_t)m * NBLK + blockIdx.x] = best;
    }
  }
}

// ---------------- kernel 3: argmax from block maxima + fp32 rescue ---------
// Global approx max from the 782 packed block maxima; blocks within
// delta=2e-3 of the max get their 64-score segment rescanned; candidates get
// exact fp32 rescoring (argmax of dot/bn is monotonic-equal to the reference
// score since qn is constant per row).
__global__ __launch_bounds__(256) void argmax_rescue(
    const unsigned long long* __restrict__ bm, const float* __restrict__ scores,
    const float* __restrict__ q, const float* __restrict__ bank,
    float* __restrict__ out_idx) {
  const int b = blockIdx.x, tid = threadIdx.x;
  const int w = tid >> 6, lane = tid & 63;
  const unsigned long long* rbm = bm + (size_t)b * NBLK;

  unsigned long long pmax = 0ull;
  for (int i = tid; i < NBLK; i += 256) {
    const unsigned long long v = rbm[i];
    pmax = v > pmax ? v : pmax;
  }
#pragma unroll
  for (int o = 32; o > 0; o >>= 1) {
    const unsigned long long v = __shfl_down(pmax, o, 64);
    pmax = v > pmax ? v : pmax;
  }
  __shared__ unsigned long long red[4];
  if (lane == 0) red[w] = pmax;
  __syncthreads();
  unsigned long long gmax = red[0];
#pragma unroll
  for (int i = 1; i < 4; ++i) gmax = red[i] > gmax ? red[i] : gmax;
  const float thr = deordf((unsigned int)(gmax >> 32)) - 2e-3f;

  __shared__ int cand[64];
  __shared__ int cnt;
  if (tid == 0) cnt = 0;
  __syncthreads();
  const float* srow = scores + (size_t)b * NB;
  for (int i = tid; i < NBLK; i += 256) {
    const float bmf = deordf((unsigned int)(rbm[i] >> 32));
    if (bmf >= thr) {  // rare (1-3 blocks): rescan its 64 scores
      const int base = i * BN;
      const int lim = min(BN, NB - base);
      for (int j = 0; j < lim; ++j) {
        if (srow[base + j] >= thr) {
          const int c = atomicAdd(&cnt, 1);
          if (c < 64) cand[c] = base + j;
        }
      }
    }
  }
  __syncthreads();
  const int nc = min(cnt, 64);

  __shared__ float dd[4], ss[4];
  float best = -1e30f;
  int bidx = 0x7fffffff;
  const float* qrow = q + (size_t)b * KD;
  for (int c = 0; c < nc; ++c) {
    const int idx = cand[c];
    const float* brow = bank + (size_t)idx * KD;
    float4 bv0 = *(const float4*)(brow + tid * 8);
    float4 bv1 = *(const float4*)(brow + tid * 8 + 4);
    float4 qv0 = *(const float4*)(qrow + tid * 8);
    float4 qv1 = *(const float4*)(qrow + tid * 8 + 4);
    float d = 0.f, s = 0.f;
    d = fmaf(qv0.x, bv0.x, d);
    s = fmaf(bv0.x, bv0.x, s);
    d = fmaf(qv0.y, bv0.y, d);
    s = fmaf(bv0.y, bv0.y, s);
    d = fmaf(qv0.z, bv0.z, d);
    s = fmaf(bv0.z, bv0.z, s);
    d = fmaf(qv0.w, bv0.w, d);
    s = fmaf(bv0.w, bv0.w, s);
    d = fmaf(qv1.x, bv1.x, d);
    s = fmaf(bv1.x, bv1.x, s);
    d = fmaf(qv1.y, bv1.y, d);
    s = fmaf(bv1.y, bv1.y, s);
    d = fmaf(qv1.z, bv1.z, d);
    s = fmaf(bv1.z, bv1.z, s);
    d = fmaf(qv1.w, bv1.w, d);
    s = fmaf(bv1.w, bv1.w, s);
    d = wave_sum(d);
    s = wave_sum(s);
    if (lane == 0) {
      dd[w] = d;
      ss[w] = s;
    }
    __syncthreads();
    const float dt = dd[0] + dd[1] + dd[2] + dd[3];
    const float st = ss[0] + ss[1] + ss[2] + ss[3];
    const float sc = dt / fmaxf(sqrtf(st), 1e-12f);
    if (sc > best || (sc == best && idx < bidx)) {
      best = sc;
      bidx = idx;
    }
    __syncthreads();
  }
  if (tid == 0) out_idx[b] = (float)bidx;
}

extern "C" void kernel_launch(void* const* d_in, const int* in_sizes, int n_in,
                              void* d_out, int out_size, void* d_ws,
                              size_t ws_size, hipStream_t stream) {
  const float* queries = (const float*)d_in[0];  // [256, 2048] fp32
  const float* bank = (const float*)d_in[1];     // [50000, 2048] fp32
  float* out = (float*)d_out;                    // [256 idx | 256*50000 scores]
  float* out_scores = out + MQ;

  char* ws = (char*)d_ws;
  unsigned short* qbf = (unsigned short*)ws;                 // 1 MB bf16 queries
  float* qn = (float*)(ws + (size_t)MQ * KD * 2);            // 1 KB q-norms
  unsigned long long* bm =
      (unsigned long long*)(ws + (size_t)MQ * KD * 2 + 2048);  // 1.6 MB maxima

  prep_q<<<MQ, 256, 0, stream>>>(queries, qbf, qn);
  gemm_scores<<<NBLK, 512, 0, stream>>>(bank, qbf, qn, out_scores, bm);
  argmax_rescue<<<MQ, 256, 0, stream>>>(bm, out_scores, queries, bank, out);
}